// Round 10
// baseline (501.783 us; speedup 1.0000x reference)
//
#include <hip/hip_runtime.h>
#include <hip/hip_bf16.h>
#include <math.h>

typedef __attribute__((ext_vector_type(8))) short bf16x8;
typedef __attribute__((ext_vector_type(4))) float f32x4;
typedef __attribute__((ext_vector_type(16))) float f32x16;
typedef unsigned short u16;

#define NHEAD 12

__device__ __forceinline__ u16 f2bf(float f) {
  __hip_bfloat16 h = __float2bfloat16(f);
  return __builtin_bit_cast(u16, h);
}

__device__ __forceinline__ void gload16(const void* g, void* l) {
  __builtin_amdgcn_global_load_lds(
      (const __attribute__((address_space(1))) void*)g,
      (__attribute__((address_space(3))) void*)l, 16, 0, 0);
}

// ---------------- all weights fp32 -> bf16, packed dst ----------------
__global__ void cvt_all(const float* __restrict__ s0, const float* __restrict__ s1,
                        const float* __restrict__ s2, const float* __restrict__ s3,
                        u16* __restrict__ d) {
  int i = blockIdx.x * 256 + threadIdx.x;  // total 1769472
  if (i >= 1769472) return;
  float v;
  if (i < 442368) v = s0[i];
  else if (i < 589824) v = s1[i - 442368];
  else if (i < 1179648) v = s2[i - 589824];
  else v = s3[i - 1179648];
  d[i] = f2bf(v);
}

// ---------------- relative-position bias table [12][64][64] ----------------
__global__ void build_bias(const float* __restrict__ rpb, float* __restrict__ bt) {
  int i = blockIdx.x * 256 + threadIdx.x;
  if (i >= NHEAD * 4096) return;
  int h = i >> 12;
  int q = (i >> 6) & 63;
  int k = i & 63;
  int qi = q >> 3, qj = q & 7, ki = k >> 3, kj = k & 7;
  int idx = (qi - ki + 7) * 15 + (qj - kj + 7);
  bt[i] = rpb[idx * NHEAD + h];
}

// ---------------- LayerNorm: fp32 in -> bf16 out, C=384, 1 wave/row ----------------
__global__ __launch_bounds__(256) void ln_k(const float* __restrict__ x,
                                            const float* __restrict__ g,
                                            const float* __restrict__ b,
                                            u16* __restrict__ out) {
  int row = (blockIdx.x << 2) + (threadIdx.x >> 6);
  int lane = threadIdx.x & 63;
  const float* xr = x + (size_t)row * 384;
  float v[6];
  float s = 0.f;
#pragma unroll
  for (int i = 0; i < 6; ++i) { v[i] = xr[lane + (i << 6)]; s += v[i]; }
#pragma unroll
  for (int o = 32; o; o >>= 1) s += __shfl_xor(s, o, 64);
  float mu = s * (1.f / 384.f);
  float vs = 0.f;
#pragma unroll
  for (int i = 0; i < 6; ++i) { float d0 = v[i] - mu; vs += d0 * d0; }
#pragma unroll
  for (int o = 32; o; o >>= 1) vs += __shfl_xor(vs, o, 64);
  float rs = rsqrtf(vs * (1.f / 384.f) + 1e-5f);
  u16* orow = out + (size_t)row * 384;
#pragma unroll
  for (int i = 0; i < 6; ++i) {
    int c = lane + (i << 6);
    orow[c] = f2bf((v[i] - mu) * rs * g[c] + b[c]);
  }
}

// ---------------- m97-style GEMM, 32x32x16 fragment engine ----------------
// out[M,N] = A[M,K](bf16) @ W[N,K]^T(bf16) + bias, epilogues:
// EP 0: +bias -> bf16 (QKV)   EP 1: +bias+res -> fp32 (proj)
// EP 2: +bias gelu -> bf16 (FC1)   EP 3: +bias+res -> fp32 (FC2)
// Block 256x96 (4 waves stacked M, wave tile 64x96 = 2x3 frags of 32x32),
// BK=64, 44KB LDS single buffer -> 3 blocks/CU. 2 barriers per K-step;
// cross-block phase stagger hides the stage/barrier chain.
// 32x32x16 frags: 2x FLOP per LDS byte vs 16x16x32 and 20% higher MFMA peak.
// XOR swizzle: row r, 16B slot s holds global col-block s^(r&7); read slot
// (kk*2 + (lane>>5)) ^ (lane&7)  [2-way max, free].
template <int EP>
__global__ __launch_bounds__(256, 3) void gemmA(const u16* __restrict__ A,
                                                const u16* __restrict__ W,
                                                const float* __restrict__ bias,
                                                const float* __restrict__ res,
                                                void* __restrict__ outp,
                                                int N, int K, int nCol) {
  __shared__ u16 As[256 * 64];
  __shared__ u16 Bs[96 * 64];
  const int tid = threadIdx.x;
  const int wave = tid >> 6, lane = tid & 63;
  const int nwg = gridDim.x, cpx = nwg >> 3;
  const int lin = (blockIdx.x & 7) * cpx + (blockIdx.x >> 3);
  const int rowT = lin / nCol;
  const int colT = lin - rowT * nCol;
  const int rowBase = rowT << 8;
  const int colBase = colT * 96;
  const int nK = K >> 6;

  // staging: round c covers rows c*32 + (tid>>3), slot s = tid&7; fetched
  // global 16B col-block = s ^ (row&7) = (tid&7) ^ ((tid>>3)&7).
  const int g16 = (tid & 7) ^ ((tid >> 3) & 7);
  const u16* Asrc = A + (size_t)(rowBase + (tid >> 3)) * K + (g16 << 3);
  const u16* Wsrc = W + (size_t)(colBase + (tid >> 3)) * K + (g16 << 3);
  const int ldst = tid << 3;  // u16 idx; +c*2048 per round

  const int l31 = lane & 31;
  const int lh = lane >> 5;   // k-half
  const int rx = lane & 7;
  const int arow = (wave << 6) + l31;  // wave covers rows wave*64..+63

  f32x16 acc[2][3] = {};

  for (int j = 0; j < nK; ++j) {
    const size_t k0 = (size_t)j << 6;
#pragma unroll
    for (int c = 0; c < 8; ++c)
      gload16(Asrc + (size_t)(c << 5) * K + k0, &As[(c << 11) + ldst]);
#pragma unroll
    for (int c = 0; c < 3; ++c)
      gload16(Wsrc + (size_t)(c << 5) * K + k0, &Bs[(c << 11) + ldst]);
    __syncthreads();
#pragma unroll
    for (int kk = 0; kk < 4; ++kk) {
      const int slot = (((kk << 1) + lh) ^ rx) << 3;
      bf16x8 aF[2], bF[3];
#pragma unroll
      for (int m = 0; m < 2; ++m)
        aF[m] = *(const bf16x8*)&As[(arow + (m << 5)) * 64 + slot];
#pragma unroll
      for (int n = 0; n < 3; ++n)
        bF[n] = *(const bf16x8*)&Bs[((n << 5) + l31) * 64 + slot];
#pragma unroll
      for (int m = 0; m < 2; ++m)
#pragma unroll
        for (int n = 0; n < 3; ++n)
          acc[m][n] = __builtin_amdgcn_mfma_f32_32x32x16_bf16(aF[m], bF[n], acc[m][n], 0, 0, 0);
    }
    __syncthreads();
  }

  float bv[3];
#pragma unroll
  for (int n = 0; n < 3; ++n) bv[n] = bias[colBase + (n << 5) + l31];

#pragma unroll
  for (int m = 0; m < 2; ++m) {
#pragma unroll
    for (int r = 0; r < 16; ++r) {
      const int row = rowBase + (wave << 6) + (m << 5) + (r & 3) + (((r >> 2)) << 3) + (lh << 2);
      const size_t rowl = (size_t)row;
#pragma unroll
      for (int n = 0; n < 3; ++n) {
        const int col = colBase + (n << 5) + l31;
        float y = acc[m][n][r] + bv[n];
        if (EP == 0) {
          ((u16*)outp)[rowl * N + col] = f2bf(y);
        } else if (EP == 1) {
          ((float*)outp)[rowl * N + col] = y + res[rowl * N + col];
        } else if (EP == 2) {
          // gelu = y * sigmoid(2u); exact algebraic rewrite of tanh form
          float y2 = y * y;
          float t = __builtin_fmaf(y2, 0.1029434f, 2.3022118f);
          float e = __builtin_amdgcn_exp2f(-(y * t));
          y = y * __builtin_amdgcn_rcpf(1.f + e);
          ((u16*)outp)[rowl * N + col] = f2bf(y);
        } else {
          ((float*)outp)[rowl * N + col] = y + res[rowl * N + col];
        }
      }
    }
  }
}

// ---------------- window attention: one block per (window, head) ----------------
// XCD swizzle: 12 consecutive logical ids (= the 12 heads of one window) land
// in one XCD chunk so they share the window's qkv rows in that XCD's L2.
__global__ __launch_bounds__(256) void attn_k(const u16* __restrict__ qkv,
                                              const float* __restrict__ bias_tab,
                                              u16* __restrict__ o) {
  const int cpx = gridDim.x >> 3;
  const int lin = (blockIdx.x & 7) * cpx + (blockIdx.x >> 3);
  const int w = lin / NHEAD;
  const int h = lin - w * NHEAD;
  const int tid = threadIdx.x, wave = tid >> 6, lane = tid & 63;
  __shared__ u16 q_s[64 * 32];
  __shared__ u16 k_s[64 * 32];
  __shared__ u16 vt_s[32 * 64];
  __shared__ u16 p_s[4][16 * 72];
  const int b = w >> 6;
  const int wim = w & 63;
  const int wr0 = (wim >> 3) << 3, wc0 = (wim & 7) << 3;
  {
    const int r = tid >> 2, d0 = (tid & 3) << 3;
    const int pr = r >> 3, pc = r & 7;
    const int orow = (wr0 + pr + 4) & 63, ocol = (wc0 + pc + 4) & 63;
    const size_t t = ((size_t)b << 12) + (orow << 6) + ocol;
    const u16* base = qkv + t * 1152 + h * 32 + d0;
    *(uint4*)&q_s[r * 32 + d0] = *(const uint4*)(base);
    *(uint4*)&k_s[r * 32 + d0] = *(const uint4*)(base + 384);
    u16 vv[8];
    *(uint4*)vv = *(const uint4*)(base + 768);
#pragma unroll
    for (int j = 0; j < 8; ++j) vt_s[(d0 + j) * 64 + r] = vv[j];
  }
  __syncthreads();
  const int cIdx = lane & 15, rgrp = lane >> 4;
  const f32x4 zz = {0.f, 0.f, 0.f, 0.f};
  bf16x8 qa = *(const bf16x8*)&q_s[((wave << 4) + cIdx) * 32 + (rgrp << 3)];
  f32x4 s_acc[4];
#pragma unroll
  for (int n = 0; n < 4; ++n) {
    bf16x8 kb = *(const bf16x8*)&k_s[((n << 4) + cIdx) * 32 + (rgrp << 3)];
    s_acc[n] = __builtin_amdgcn_mfma_f32_16x16x32_bf16(qa, kb, zz, 0, 0, 0);
  }
  const float scale = 0.1767766952966369f;
  float mrow[4] = {-1e30f, -1e30f, -1e30f, -1e30f};
  const float* bt = bias_tab + h * 4096 + ((wave << 4) + (rgrp << 2)) * 64 + cIdx;
#pragma unroll
  for (int n = 0; n < 4; ++n)
#pragma unroll
    for (int j = 0; j < 4; ++j) {
      float val = s_acc[n][j] * scale + bt[j * 64 + (n << 4)];
      s_acc[n][j] = val;
      mrow[j] = fmaxf(mrow[j], val);
    }
#pragma unroll
  for (int j = 0; j < 4; ++j)
#pragma unroll
    for (int o2 = 1; o2 < 16; o2 <<= 1) mrow[j] = fmaxf(mrow[j], __shfl_xor(mrow[j], o2, 64));
  float srow[4] = {0.f, 0.f, 0.f, 0.f};
#pragma unroll
  for (int n = 0; n < 4; ++n)
#pragma unroll
    for (int j = 0; j < 4; ++j) {
      float e = __expf(s_acc[n][j] - mrow[j]);
      s_acc[n][j] = e;
      srow[j] += e;
    }
#pragma unroll
  for (int j = 0; j < 4; ++j)
#pragma unroll
    for (int o2 = 1; o2 < 16; o2 <<= 1) srow[j] += __shfl_xor(srow[j], o2, 64);
  float rinv[4];
#pragma unroll
  for (int j = 0; j < 4; ++j) rinv[j] = 1.f / srow[j];
  u16* pw = p_s[wave];
#pragma unroll
  for (int n = 0; n < 4; ++n)
#pragma unroll
    for (int j = 0; j < 4; ++j)
      pw[((rgrp << 2) + j) * 72 + (n << 4) + cIdx] = f2bf(s_acc[n][j] * rinv[j]);
  f32x4 o_acc[2] = {};
#pragma unroll
  for (int kk = 0; kk < 2; ++kk) {
    bf16x8 pa = *(const bf16x8*)&pw[cIdx * 72 + (kk << 5) + (rgrp << 3)];
#pragma unroll
    for (int c2 = 0; c2 < 2; ++c2) {
      bf16x8 vb = *(const bf16x8*)&vt_s[((c2 << 4) + cIdx) * 64 + (kk << 5) + (rgrp << 3)];
      o_acc[c2] = __builtin_amdgcn_mfma_f32_16x16x32_bf16(pa, vb, o_acc[c2], 0, 0, 0);
    }
  }
#pragma unroll
  for (int c2 = 0; c2 < 2; ++c2)
#pragma unroll
    for (int j = 0; j < 4; ++j) {
      const int p = (wave << 4) + (rgrp << 2) + j;
      const int pr = p >> 3, pc = p & 7;
      const int orow = (wr0 + pr + 4) & 63, ocol = (wc0 + pc + 4) & 63;
      const size_t t = ((size_t)b << 12) + (orow << 6) + ocol;
      o[t * 384 + h * 32 + (c2 << 4) + cIdx] = f2bf(o_acc[c2][j]);
    }
}

extern "C" void kernel_launch(void* const* d_in, const int* in_sizes, int n_in,
                              void* d_out, int out_size, void* d_ws, size_t ws_size,
                              hipStream_t stream) {
  const float* x = (const float*)d_in[0];
  const float* n1g = (const float*)d_in[1];
  const float* n1b = (const float*)d_in[2];
  const float* qkv_w = (const float*)d_in[3];
  const float* qkv_b = (const float*)d_in[4];
  const float* proj_w = (const float*)d_in[5];
  const float* proj_b = (const float*)d_in[6];
  const float* rpb = (const float*)d_in[7];
  const float* n2g = (const float*)d_in[8];
  const float* n2b = (const float*)d_in[9];
  const float* fc1_w = (const float*)d_in[10];
  const float* fc1_b = (const float*)d_in[11];
  const float* fc2_w = (const float*)d_in[12];
  const float* fc2_b = (const float*)d_in[13];

  char* ws = (char*)d_ws;
  u16* wqkv = (u16*)(ws + 0);                // 442368 elems
  u16* wproj = (u16*)(ws + 884736);          // 147456
  u16* wfc1 = (u16*)(ws + 1179648);          // 589824
  u16* wfc2 = (u16*)(ws + 2359296);          // 589824
  float* bias_tab = (float*)(ws + 3538944);
  u16* qkv = (u16*)(ws + 3735552);           // region A (qkv, then m1)
  u16* m1 = qkv;
  u16* hbuf = (u16*)(ws + 205062144);        // region B (h -> o -> h2)
  u16* obuf = hbuf;
  float* x1 = (float*)d_out;

  cvt_all<<<(1769472 + 255) / 256, 256, 0, stream>>>(qkv_w, proj_w, fc1_w, fc2_w, wqkv);
  build_bias<<<192, 256, 0, stream>>>(rpb, bias_tab);

  ln_k<<<16384, 256, 0, stream>>>(x, n1g, n1b, hbuf);
  gemmA<0><<<3072, 256, 0, stream>>>(hbuf, wqkv, qkv_b, nullptr, qkv, 1152, 384, 12);
  attn_k<<<12288, 256, 0, stream>>>(qkv, bias_tab, obuf);
  gemmA<1><<<1024, 256, 0, stream>>>(obuf, wproj, proj_b, x, x1, 384, 384, 4);
  ln_k<<<16384, 256, 0, stream>>>(x1, n2g, n2b, hbuf);
  gemmA<2><<<4096, 256, 0, stream>>>(hbuf, wfc1, fc1_b, nullptr, m1, 1536, 384, 16);
  gemmA<3><<<1024, 256, 0, stream>>>(m1, wfc2, fc2_b, x1, (float*)d_out, 384, 1536, 4);
}

// Round 11
// 489.761 us; speedup vs baseline: 1.0245x; 1.0245x over previous
//
#include <hip/hip_runtime.h>
#include <hip/hip_bf16.h>
#include <math.h>

typedef __attribute__((ext_vector_type(8))) short bf16x8;
typedef __attribute__((ext_vector_type(4))) float f32x4;
typedef unsigned short u16;

#define NHEAD 12

__device__ __forceinline__ u16 f2bf(float f) {
  __hip_bfloat16 h = __float2bfloat16(f);
  return __builtin_bit_cast(u16, h);
}

__device__ __forceinline__ void gload16(const void* g, void* l) {
  __builtin_amdgcn_global_load_lds(
      (const __attribute__((address_space(1))) void*)g,
      (__attribute__((address_space(3))) void*)l, 16, 0, 0);
}

// ---------------- all weights fp32 -> bf16, packed dst ----------------
__global__ void cvt_all(const float* __restrict__ s0, const float* __restrict__ s1,
                        const float* __restrict__ s2, const float* __restrict__ s3,
                        u16* __restrict__ d) {
  int i = blockIdx.x * 256 + threadIdx.x;  // total 1769472
  if (i >= 1769472) return;
  float v;
  if (i < 442368) v = s0[i];
  else if (i < 589824) v = s1[i - 442368];
  else if (i < 1179648) v = s2[i - 589824];
  else v = s3[i - 1179648];
  d[i] = f2bf(v);
}

// ---------------- relative-position bias table [12][64][64] ----------------
__global__ void build_bias(const float* __restrict__ rpb, float* __restrict__ bt) {
  int i = blockIdx.x * 256 + threadIdx.x;
  if (i >= NHEAD * 4096) return;
  int h = i >> 12;
  int q = (i >> 6) & 63;
  int k = i & 63;
  int qi = q >> 3, qj = q & 7, ki = k >> 3, kj = k & 7;
  int idx = (qi - ki + 7) * 15 + (qj - kj + 7);
  bt[i] = rpb[idx * NHEAD + h];
}

// ---------------- LayerNorm (ln1): fp32 in -> bf16 out, C=384, 1 wave/row ----------------
__global__ __launch_bounds__(256) void ln_k(const float* __restrict__ x,
                                            const float* __restrict__ g,
                                            const float* __restrict__ b,
                                            u16* __restrict__ out) {
  int row = (blockIdx.x << 2) + (threadIdx.x >> 6);
  int lane = threadIdx.x & 63;
  const float* xr = x + (size_t)row * 384;
  float v[6];
  float s = 0.f;
#pragma unroll
  for (int i = 0; i < 6; ++i) { v[i] = xr[lane + (i << 6)]; s += v[i]; }
#pragma unroll
  for (int o = 32; o; o >>= 1) s += __shfl_xor(s, o, 64);
  float mu = s * (1.f / 384.f);
  float vs = 0.f;
#pragma unroll
  for (int i = 0; i < 6; ++i) { float d0 = v[i] - mu; vs += d0 * d0; }
#pragma unroll
  for (int o = 32; o; o >>= 1) vs += __shfl_xor(vs, o, 64);
  float rs = rsqrtf(vs * (1.f / 384.f) + 1e-5f);
  u16* orow = out + (size_t)row * 384;
#pragma unroll
  for (int i = 0; i < 6; ++i) {
    int c = lane + (i << 6);
    orow[c] = f2bf((v[i] - mu) * rs * g[c] + b[c]);
  }
}

// ---------------- m97-style GEMM (R6 config: best measured) ----------------
// out[M,N] = A[M,K](bf16) @ W[N,K]^T(bf16) + bias, epilogues:
// EP 0: +bias -> bf16 (QKV)   EP 2: +bias gelu -> bf16 (FC1)
// EP 3: +bias+res -> fp32 (FC2)
// 128x128 tile, BK=64, 256 threads = 4 waves (2x2), single 32KB LDS buffer,
// 2 barriers per K-step; co-resident blocks' staggered phases hide the drain.
// XOR swizzle: row r, 16B slot s holds global col-block s^(r&7); read at
// slot (kk*4 + (lane>>4)) ^ (r&7)  -> 2-way max (free).
template <int EP>
__global__ __launch_bounds__(256, 4) void gemmA(const u16* __restrict__ A,
                                                const u16* __restrict__ W,
                                                const float* __restrict__ bias,
                                                const float* __restrict__ res,
                                                void* __restrict__ outp,
                                                int N, int K, int nCol) {
  __shared__ u16 As[128 * 64];
  __shared__ u16 Bs[128 * 64];
  const int tid = threadIdx.x;
  const int wave = tid >> 6, lane = tid & 63;
  const int wm = wave >> 1, wn = wave & 1;
  const int nwg = gridDim.x, cpx = nwg >> 3;
  const int lin = (blockIdx.x & 7) * cpx + (blockIdx.x >> 3);
  const int rowT = lin / nCol;
  const int colT = lin - rowT * nCol;
  const int rowBase = rowT << 7;
  const int colBase = colT << 7;
  const int nK = K >> 6;

  const int g16 = (tid & 7) ^ ((tid >> 3) & 7);
  const u16* Asrc = A + (size_t)(rowBase + (tid >> 3)) * K + (g16 << 3);
  const u16* Wsrc = W + (size_t)(colBase + (tid >> 3)) * K + (g16 << 3);
  const int ldst = tid << 3;

  const int q4 = lane >> 4;
  const int rx = lane & 7;
  const int arow = (wm << 6) + (lane & 15);
  const int brow = (wn << 6) + (lane & 15);

  f32x4 acc[4][4] = {};

  for (int j = 0; j < nK; ++j) {
    const size_t k0 = (size_t)j << 6;
#pragma unroll
    for (int c = 0; c < 4; ++c) {
      gload16(Asrc + (size_t)(c << 5) * K + k0, &As[(c << 11) + ldst]);
      gload16(Wsrc + (size_t)(c << 5) * K + k0, &Bs[(c << 11) + ldst]);
    }
    __syncthreads();
#pragma unroll
    for (int kk = 0; kk < 2; ++kk) {
      const int slot = (((kk << 2) + q4) ^ rx) << 3;
      bf16x8 aF[4], bF[4];
#pragma unroll
      for (int m = 0; m < 4; ++m)
        aF[m] = *(const bf16x8*)&As[(arow + (m << 4)) * 64 + slot];
#pragma unroll
      for (int n = 0; n < 4; ++n)
        bF[n] = *(const bf16x8*)&Bs[(brow + (n << 4)) * 64 + slot];
#pragma unroll
      for (int m = 0; m < 4; ++m)
#pragma unroll
        for (int n = 0; n < 4; ++n)
          acc[m][n] = __builtin_amdgcn_mfma_f32_16x16x32_bf16(aF[m], bF[n], acc[m][n], 0, 0, 0);
    }
    __syncthreads();
  }

#pragma unroll
  for (int m = 0; m < 4; ++m) {
#pragma unroll
    for (int n = 0; n < 4; ++n) {
      const int col = colBase + (wn << 6) + (n << 4) + (lane & 15);
      const int row0 = rowBase + (wm << 6) + (m << 4) + ((lane >> 4) << 2);
      const float bv = bias[col];
#pragma unroll
      for (int jj = 0; jj < 4; ++jj) {
        const size_t row = (size_t)(row0 + jj);
        float y = acc[m][n][jj] + bv;
        if (EP == 0) {
          ((u16*)outp)[row * N + col] = f2bf(y);
        } else if (EP == 2) {
          // gelu = y * sigmoid(2u); exact algebraic rewrite of tanh form
          float y2 = y * y;
          float t = __builtin_fmaf(y2, 0.1029434f, 2.3022118f);
          float e = __builtin_amdgcn_exp2f(-(y * t));
          y = y * __builtin_amdgcn_rcpf(1.f + e);
          ((u16*)outp)[row * N + col] = f2bf(y);
        } else {
          ((float*)outp)[row * N + col] = y + res[row * N + col];
        }
      }
    }
  }
}

// ---------------- proj + residual + LN2 fused ----------------
// x1 = x + (o @ Wp^T + bp)  [fp32 -> d_out];  h2 = LN(x1)*g2+b2 [bf16 -> hbuf]
// Block = 64 rows x full N=384 (row stats block-local). 512 thr = 8 col-waves,
// wave tile 64x48, acc[4][3] = 48 regs. LDS: A 8KB + W 48KB = 56KB
// -> 2 blocks/CU (launch_bounds(512,4)). Same staging/XOR swizzle as gemmA.
// In-place h2 over obuf is safe: block writes only rows it already consumed.
__global__ __launch_bounds__(512, 4) void projln_k(const u16* __restrict__ A,
                                                   const u16* __restrict__ W,
                                                   const float* __restrict__ bias,
                                                   const float* __restrict__ res,
                                                   const float* __restrict__ g2,
                                                   const float* __restrict__ b2,
                                                   float* __restrict__ x1,
                                                   u16* __restrict__ h2) {
  __shared__ u16 As[64 * 64];
  __shared__ u16 Ws[384 * 64];
  __shared__ float red[2][8][64];
  const int tid = threadIdx.x;
  const int wave = tid >> 6, lane = tid & 63;
  const int nwg = gridDim.x, cpx = nwg >> 3;
  const int lin = (blockIdx.x & 7) * cpx + (blockIdx.x >> 3);
  const int rowBase = lin << 6;

  const int g16 = (tid & 7) ^ ((tid >> 3) & 7);
  const u16* Asrc = A + (size_t)(rowBase + (tid >> 3)) * 384 + (g16 << 3);
  const u16* Wsrc = W + (size_t)(tid >> 3) * 384 + (g16 << 3);
  const int ldst = tid << 3;
  const int q4 = lane >> 4, rx = lane & 7;
  const int arow = lane & 15;
  const int brow = wave * 48 + (lane & 15);

  f32x4 acc[4][3] = {};

  for (int j = 0; j < 6; ++j) {
    const size_t k0 = (size_t)j << 6;
    gload16(Asrc + k0, &As[ldst & 8191]);       // only tids 0..511 -> 64 rows
#pragma unroll
    for (int c = 0; c < 6; ++c)
      gload16(Wsrc + (size_t)(c << 6) * 384 + k0, &Ws[(c << 12) + ldst]);
    __syncthreads();
#pragma unroll
    for (int kk = 0; kk < 2; ++kk) {
      const int slot = (((kk << 2) + q4) ^ rx) << 3;
      bf16x8 aF[4], bF[3];
#pragma unroll
      for (int m = 0; m < 4; ++m)
        aF[m] = *(const bf16x8*)&As[(arow + (m << 4)) * 64 + slot];
#pragma unroll
      for (int n = 0; n < 3; ++n)
        bF[n] = *(const bf16x8*)&Ws[(brow + (n << 4)) * 64 + slot];
#pragma unroll
      for (int m = 0; m < 4; ++m)
#pragma unroll
        for (int n = 0; n < 3; ++n)
          acc[m][n] = __builtin_amdgcn_mfma_f32_16x16x32_bf16(aF[m], bF[n], acc[m][n], 0, 0, 0);
    }
    __syncthreads();
  }

  float bv[3], gv[3], b2v[3];
#pragma unroll
  for (int n = 0; n < 3; ++n) {
    int col = wave * 48 + (n << 4) + (lane & 15);
    bv[n] = bias[col]; gv[n] = g2[col]; b2v[n] = b2[col];
  }
  // finalize val = acc + bias + res; per-row partial sums over this wave's 48 cols
#pragma unroll
  for (int m = 0; m < 4; ++m) {
#pragma unroll
    for (int jj = 0; jj < 4; ++jj) {
      const int rl = (m << 4) + (q4 << 2) + jj;  // 0..63
      const int row = rowBase + rl;
      const float* rr = res + (size_t)row * 384 + wave * 48 + (lane & 15);
      float s = 0.f, sq = 0.f;
#pragma unroll
      for (int n = 0; n < 3; ++n) {
        float v = acc[m][n][jj] + bv[n] + rr[n << 4];
        acc[m][n][jj] = v;
        s += v; sq += v * v;
      }
#pragma unroll
      for (int o2 = 1; o2 < 16; o2 <<= 1) {
        s += __shfl_xor(s, o2, 64);
        sq += __shfl_xor(sq, o2, 64);
      }
      if ((lane & 15) == 0) { red[0][wave][rl] = s; red[1][wave][rl] = sq; }
    }
  }
  __syncthreads();
#pragma unroll
  for (int m = 0; m < 4; ++m) {
#pragma unroll
    for (int jj = 0; jj < 4; ++jj) {
      const int rl = (m << 4) + (q4 << 2) + jj;
      float s = 0.f, sq = 0.f;
#pragma unroll
      for (int wv = 0; wv < 8; ++wv) { s += red[0][wv][rl]; sq += red[1][wv][rl]; }
      float mu = s * (1.f / 384.f);
      float var = sq * (1.f / 384.f) - mu * mu;
      float rs = rsqrtf(var + 1e-5f);
      const int row = rowBase + rl;
      float* xr = x1 + (size_t)row * 384;
      u16* hr = h2 + (size_t)row * 384;
#pragma unroll
      for (int n = 0; n < 3; ++n) {
        int c = wave * 48 + (n << 4) + (lane & 15);
        float v = acc[m][n][jj];
        xr[c] = v;
        hr[c] = f2bf((v - mu) * rs * gv[n] + b2v[n]);
      }
    }
  }
}

// ---------------- window attention: one block per (window, head) ----------------
// XCD swizzle: 12 consecutive logical ids (= the 12 heads of one window) land
// in one XCD chunk so they share the window's qkv rows in that XCD's L2.
__global__ __launch_bounds__(256) void attn_k(const u16* __restrict__ qkv,
                                              const float* __restrict__ bias_tab,
                                              u16* __restrict__ o) {
  const int cpx = gridDim.x >> 3;
  const int lin = (blockIdx.x & 7) * cpx + (blockIdx.x >> 3);
  const int w = lin / NHEAD;
  const int h = lin - w * NHEAD;
  const int tid = threadIdx.x, wave = tid >> 6, lane = tid & 63;
  __shared__ u16 q_s[64 * 32];
  __shared__ u16 k_s[64 * 32];
  __shared__ u16 vt_s[32 * 64];
  __shared__ u16 p_s[4][16 * 72];
  const int b = w >> 6;
  const int wim = w & 63;
  const int wr0 = (wim >> 3) << 3, wc0 = (wim & 7) << 3;
  {
    const int r = tid >> 2, d0 = (tid & 3) << 3;
    const int pr = r >> 3, pc = r & 7;
    const int orow = (wr0 + pr + 4) & 63, ocol = (wc0 + pc + 4) & 63;
    const size_t t = ((size_t)b << 12) + (orow << 6) + ocol;
    const u16* base = qkv + t * 1152 + h * 32 + d0;
    *(uint4*)&q_s[r * 32 + d0] = *(const uint4*)(base);
    *(uint4*)&k_s[r * 32 + d0] = *(const uint4*)(base + 384);
    u16 vv[8];
    *(uint4*)vv = *(const uint4*)(base + 768);
#pragma unroll
    for (int j = 0; j < 8; ++j) vt_s[(d0 + j) * 64 + r] = vv[j];
  }
  __syncthreads();
  const int cIdx = lane & 15, rgrp = lane >> 4;
  const f32x4 zz = {0.f, 0.f, 0.f, 0.f};
  bf16x8 qa = *(const bf16x8*)&q_s[((wave << 4) + cIdx) * 32 + (rgrp << 3)];
  f32x4 s_acc[4];
#pragma unroll
  for (int n = 0; n < 4; ++n) {
    bf16x8 kb = *(const bf16x8*)&k_s[((n << 4) + cIdx) * 32 + (rgrp << 3)];
    s_acc[n] = __builtin_amdgcn_mfma_f32_16x16x32_bf16(qa, kb, zz, 0, 0, 0);
  }
  const float scale = 0.1767766952966369f;
  float mrow[4] = {-1e30f, -1e30f, -1e30f, -1e30f};
  const float* bt = bias_tab + h * 4096 + ((wave << 4) + (rgrp << 2)) * 64 + cIdx;
#pragma unroll
  for (int n = 0; n < 4; ++n)
#pragma unroll
    for (int j = 0; j < 4; ++j) {
      float val = s_acc[n][j] * scale + bt[j * 64 + (n << 4)];
      s_acc[n][j] = val;
      mrow[j] = fmaxf(mrow[j], val);
    }
#pragma unroll
  for (int j = 0; j < 4; ++j)
#pragma unroll
    for (int o2 = 1; o2 < 16; o2 <<= 1) mrow[j] = fmaxf(mrow[j], __shfl_xor(mrow[j], o2, 64));
  float srow[4] = {0.f, 0.f, 0.f, 0.f};
#pragma unroll
  for (int n = 0; n < 4; ++n)
#pragma unroll
    for (int j = 0; j < 4; ++j) {
      float e = __expf(s_acc[n][j] - mrow[j]);
      s_acc[n][j] = e;
      srow[j] += e;
    }
#pragma unroll
  for (int j = 0; j < 4; ++j)
#pragma unroll
    for (int o2 = 1; o2 < 16; o2 <<= 1) srow[j] += __shfl_xor(srow[j], o2, 64);
  float rinv[4];
#pragma unroll
  for (int j = 0; j < 4; ++j) rinv[j] = 1.f / srow[j];
  u16* pw = p_s[wave];
#pragma unroll
  for (int n = 0; n < 4; ++n)
#pragma unroll
    for (int j = 0; j < 4; ++j)
      pw[((rgrp << 2) + j) * 72 + (n << 4) + cIdx] = f2bf(s_acc[n][j] * rinv[j]);
  f32x4 o_acc[2] = {};
#pragma unroll
  for (int kk = 0; kk < 2; ++kk) {
    bf16x8 pa = *(const bf16x8*)&pw[cIdx * 72 + (kk << 5) + (rgrp << 3)];
#pragma unroll
    for (int c2 = 0; c2 < 2; ++c2) {
      bf16x8 vb = *(const bf16x8*)&vt_s[((c2 << 4) + cIdx) * 64 + (kk << 5) + (rgrp << 3)];
      o_acc[c2] = __builtin_amdgcn_mfma_f32_16x16x32_bf16(pa, vb, o_acc[c2], 0, 0, 0);
    }
  }
#pragma unroll
  for (int c2 = 0; c2 < 2; ++c2)
#pragma unroll
    for (int j = 0; j < 4; ++j) {
      const int p = (wave << 4) + (rgrp << 2) + j;
      const int pr = p >> 3, pc = p & 7;
      const int orow = (wr0 + pr + 4) & 63, ocol = (wc0 + pc + 4) & 63;
      const size_t t = ((size_t)b << 12) + (orow << 6) + ocol;
      o[t * 384 + h * 32 + (c2 << 4) + cIdx] = f2bf(o_acc[c2][j]);
    }
}

extern "C" void kernel_launch(void* const* d_in, const int* in_sizes, int n_in,
                              void* d_out, int out_size, void* d_ws, size_t ws_size,
                              hipStream_t stream) {
  const float* x = (const float*)d_in[0];
  const float* n1g = (const float*)d_in[1];
  const float* n1b = (const float*)d_in[2];
  const float* qkv_w = (const float*)d_in[3];
  const float* qkv_b = (const float*)d_in[4];
  const float* proj_w = (const float*)d_in[5];
  const float* proj_b = (const float*)d_in[6];
  const float* rpb = (const float*)d_in[7];
  const float* n2g = (const float*)d_in[8];
  const float* n2b = (const float*)d_in[9];
  const float* fc1_w = (const float*)d_in[10];
  const float* fc1_b = (const float*)d_in[11];
  const float* fc2_w = (const float*)d_in[12];
  const float* fc2_b = (const float*)d_in[13];

  char* ws = (char*)d_ws;
  u16* wqkv = (u16*)(ws + 0);                // 442368 elems
  u16* wproj = (u16*)(ws + 884736);          // 147456
  u16* wfc1 = (u16*)(ws + 1179648);          // 589824
  u16* wfc2 = (u16*)(ws + 2359296);          // 589824
  float* bias_tab = (float*)(ws + 3538944);
  u16* qkv = (u16*)(ws + 3735552);           // region A (qkv, then m1)
  u16* m1 = qkv;
  u16* hbuf = (u16*)(ws + 205062144);        // region B (h -> o -> h2)
  u16* obuf = hbuf;
  float* x1 = (float*)d_out;

  cvt_all<<<(1769472 + 255) / 256, 256, 0, stream>>>(qkv_w, proj_w, fc1_w, fc2_w, wqkv);
  build_bias<<<192, 256, 0, stream>>>(rpb, bias_tab);

  ln_k<<<16384, 256, 0, stream>>>(x, n1g, n1b, hbuf);
  gemmA<0><<<4608, 256, 0, stream>>>(hbuf, wqkv, qkv_b, nullptr, qkv, 1152, 384, 9);
  attn_k<<<12288, 256, 0, stream>>>(qkv, bias_tab, obuf);
  projln_k<<<1024, 512, 0, stream>>>(obuf, wproj, proj_b, x, n2g, n2b, x1, hbuf);
  gemmA<2><<<6144, 256, 0, stream>>>(hbuf, wfc1, fc1_b, nullptr, m1, 1536, 384, 12);
  gemmA<3><<<1536, 256, 0, stream>>>(m1, wfc2, fc2_b, x1, (float*)d_out, 384, 1536, 3);
}

// Round 12
// 474.944 us; speedup vs baseline: 1.0565x; 1.0312x over previous
//
#include <hip/hip_runtime.h>
#include <hip/hip_bf16.h>
#include <math.h>

typedef __attribute__((ext_vector_type(8))) short bf16x8;
typedef __attribute__((ext_vector_type(4))) float f32x4;
typedef unsigned short u16;

#define NHEAD 12

__device__ __forceinline__ u16 f2bf(float f) {
  __hip_bfloat16 h = __float2bfloat16(f);
  return __builtin_bit_cast(u16, h);
}

__device__ __forceinline__ void gload16(const void* g, void* l) {
  __builtin_amdgcn_global_load_lds(
      (const __attribute__((address_space(1))) void*)g,
      (__attribute__((address_space(3))) void*)l, 16, 0, 0);
}

// ---------------- all weights fp32 -> bf16, packed dst ----------------
__global__ void cvt_all(const float* __restrict__ s0, const float* __restrict__ s1,
                        const float* __restrict__ s2, const float* __restrict__ s3,
                        u16* __restrict__ d) {
  int i = blockIdx.x * 256 + threadIdx.x;  // total 1769472
  if (i >= 1769472) return;
  float v;
  if (i < 442368) v = s0[i];
  else if (i < 589824) v = s1[i - 442368];
  else if (i < 1179648) v = s2[i - 589824];
  else v = s3[i - 1179648];
  d[i] = f2bf(v);
}

// ---------------- relative-position bias table [12][64][64] ----------------
__global__ void build_bias(const float* __restrict__ rpb, float* __restrict__ bt) {
  int i = blockIdx.x * 256 + threadIdx.x;
  if (i >= NHEAD * 4096) return;
  int h = i >> 12;
  int q = (i >> 6) & 63;
  int k = i & 63;
  int qi = q >> 3, qj = q & 7, ki = k >> 3, kj = k & 7;
  int idx = (qi - ki + 7) * 15 + (qj - kj + 7);
  bt[i] = rpb[idx * NHEAD + h];
}

// ---------------- LayerNorm: fp32 in -> bf16 out, C=384, 1 wave/row ----------------
__global__ __launch_bounds__(256) void ln_k(const float* __restrict__ x,
                                            const float* __restrict__ g,
                                            const float* __restrict__ b,
                                            u16* __restrict__ out) {
  int row = (blockIdx.x << 2) + (threadIdx.x >> 6);
  int lane = threadIdx.x & 63;
  const float* xr = x + (size_t)row * 384;
  float v[6];
  float s = 0.f;
#pragma unroll
  for (int i = 0; i < 6; ++i) { v[i] = xr[lane + (i << 6)]; s += v[i]; }
#pragma unroll
  for (int o = 32; o; o >>= 1) s += __shfl_xor(s, o, 64);
  float mu = s * (1.f / 384.f);
  float vs = 0.f;
#pragma unroll
  for (int i = 0; i < 6; ++i) { float d0 = v[i] - mu; vs += d0 * d0; }
#pragma unroll
  for (int o = 32; o; o >>= 1) vs += __shfl_xor(vs, o, 64);
  float rs = rsqrtf(vs * (1.f / 384.f) + 1e-5f);
  u16* orow = out + (size_t)row * 384;
#pragma unroll
  for (int i = 0; i < 6; ++i) {
    int c = lane + (i << 6);
    orow[c] = f2bf((v[i] - mu) * rs * g[c] + b[c]);
  }
}

// ---------------- m97-style GEMM (best measured config) ----------------
// out[M,N] = A[M,K](bf16) @ W[N,K]^T(bf16) + bias, epilogues:
// EP 0: +bias -> bf16 (QKV)   EP 1: +bias+res -> fp32 (proj)
// EP 2: +bias gelu -> bf16 (FC1)   EP 3: +bias+res -> fp32 (FC2)
// 128x128 tile, BK=64, 256 threads = 4 waves (2x2), single 32KB LDS buffer,
// 2 barriers per K-step; 4 blocks/CU staggered phases hide the drain.
// XOR swizzle: row r, 16B slot s holds global col-block s^(r&7); read at
// slot (kk*4 + (lane>>4)) ^ (r&7)  -> 2-way max (free).
template <int EP>
__global__ __launch_bounds__(256, 4) void gemmA(const u16* __restrict__ A,
                                                const u16* __restrict__ W,
                                                const float* __restrict__ bias,
                                                const float* __restrict__ res,
                                                void* __restrict__ outp,
                                                int N, int K, int nCol) {
  __shared__ u16 As[128 * 64];
  __shared__ u16 Bs[128 * 64];
  const int tid = threadIdx.x;
  const int wave = tid >> 6, lane = tid & 63;
  const int wm = wave >> 1, wn = wave & 1;
  const int nwg = gridDim.x, cpx = nwg >> 3;
  const int lin = (blockIdx.x & 7) * cpx + (blockIdx.x >> 3);
  const int rowT = lin / nCol;
  const int colT = lin - rowT * nCol;
  const int rowBase = rowT << 7;
  const int colBase = colT << 7;
  const int nK = K >> 6;

  const int g16 = (tid & 7) ^ ((tid >> 3) & 7);
  const u16* Asrc = A + (size_t)(rowBase + (tid >> 3)) * K + (g16 << 3);
  const u16* Wsrc = W + (size_t)(colBase + (tid >> 3)) * K + (g16 << 3);
  const int ldst = tid << 3;

  const int q4 = lane >> 4;
  const int rx = lane & 7;
  const int arow = (wm << 6) + (lane & 15);
  const int brow = (wn << 6) + (lane & 15);

  f32x4 acc[4][4] = {};

  for (int j = 0; j < nK; ++j) {
    const size_t k0 = (size_t)j << 6;
#pragma unroll
    for (int c = 0; c < 4; ++c) {
      gload16(Asrc + (size_t)(c << 5) * K + k0, &As[(c << 11) + ldst]);
      gload16(Wsrc + (size_t)(c << 5) * K + k0, &Bs[(c << 11) + ldst]);
    }
    __syncthreads();
#pragma unroll
    for (int kk = 0; kk < 2; ++kk) {
      const int slot = (((kk << 2) + q4) ^ rx) << 3;
      bf16x8 aF[4], bF[4];
#pragma unroll
      for (int m = 0; m < 4; ++m)
        aF[m] = *(const bf16x8*)&As[(arow + (m << 4)) * 64 + slot];
#pragma unroll
      for (int n = 0; n < 4; ++n)
        bF[n] = *(const bf16x8*)&Bs[(brow + (n << 4)) * 64 + slot];
#pragma unroll
      for (int m = 0; m < 4; ++m)
#pragma unroll
        for (int n = 0; n < 4; ++n)
          acc[m][n] = __builtin_amdgcn_mfma_f32_16x16x32_bf16(aF[m], bF[n], acc[m][n], 0, 0, 0);
    }
    __syncthreads();
  }

#pragma unroll
  for (int m = 0; m < 4; ++m) {
#pragma unroll
    for (int n = 0; n < 4; ++n) {
      const int col = colBase + (wn << 6) + (n << 4) + (lane & 15);
      const int row0 = rowBase + (wm << 6) + (m << 4) + ((lane >> 4) << 2);
      const float bv = bias[col];
#pragma unroll
      for (int jj = 0; jj < 4; ++jj) {
        const size_t row = (size_t)(row0 + jj);
        float y = acc[m][n][jj] + bv;
        if (EP == 0) {
          ((u16*)outp)[row * N + col] = f2bf(y);
        } else if (EP == 1) {
          ((float*)outp)[row * N + col] = y + res[row * N + col];
        } else if (EP == 2) {
          // gelu = y * sigmoid(2u); exact algebraic rewrite of the tanh form
          float y2 = y * y;
          float t = __builtin_fmaf(y2, 0.1029434f, 2.3022118f);
          float e = __builtin_amdgcn_exp2f(-(y * t));
          y = y * __builtin_amdgcn_rcpf(1.f + e);
          ((u16*)outp)[row * N + col] = f2bf(y);
        } else {
          ((float*)outp)[row * N + col] = y + res[row * N + col];
        }
      }
    }
  }
}

// ---------------- window attention: one block per (window, head) ----------------
// XCD swizzle: 12 consecutive logical ids (= the 12 heads of one window) land
// in one XCD chunk so they share the window's qkv rows in that XCD's L2.
__global__ __launch_bounds__(256) void attn_k(const u16* __restrict__ qkv,
                                              const float* __restrict__ bias_tab,
                                              u16* __restrict__ o) {
  const int cpx = gridDim.x >> 3;
  const int lin = (blockIdx.x & 7) * cpx + (blockIdx.x >> 3);
  const int w = lin / NHEAD;
  const int h = lin - w * NHEAD;
  const int tid = threadIdx.x, wave = tid >> 6, lane = tid & 63;
  __shared__ u16 q_s[64 * 32];
  __shared__ u16 k_s[64 * 32];
  __shared__ u16 vt_s[32 * 64];
  __shared__ u16 p_s[4][16 * 72];
  const int b = w >> 6;
  const int wim = w & 63;
  const int wr0 = (wim >> 3) << 3, wc0 = (wim & 7) << 3;
  {
    const int r = tid >> 2, d0 = (tid & 3) << 3;
    const int pr = r >> 3, pc = r & 7;
    const int orow = (wr0 + pr + 4) & 63, ocol = (wc0 + pc + 4) & 63;
    const size_t t = ((size_t)b << 12) + (orow << 6) + ocol;
    const u16* base = qkv + t * 1152 + h * 32 + d0;
    *(uint4*)&q_s[r * 32 + d0] = *(const uint4*)(base);
    *(uint4*)&k_s[r * 32 + d0] = *(const uint4*)(base + 384);
    u16 vv[8];
    *(uint4*)vv = *(const uint4*)(base + 768);
#pragma unroll
    for (int j = 0; j < 8; ++j) vt_s[(d0 + j) * 64 + r] = vv[j];
  }
  __syncthreads();
  const int cIdx = lane & 15, rgrp = lane >> 4;
  const f32x4 zz = {0.f, 0.f, 0.f, 0.f};
  bf16x8 qa = *(const bf16x8*)&q_s[((wave << 4) + cIdx) * 32 + (rgrp << 3)];
  f32x4 s_acc[4];
#pragma unroll
  for (int n = 0; n < 4; ++n) {
    bf16x8 kb = *(const bf16x8*)&k_s[((n << 4) + cIdx) * 32 + (rgrp << 3)];
    s_acc[n] = __builtin_amdgcn_mfma_f32_16x16x32_bf16(qa, kb, zz, 0, 0, 0);
  }
  const float scale = 0.1767766952966369f;
  float mrow[4] = {-1e30f, -1e30f, -1e30f, -1e30f};
  const float* bt = bias_tab + h * 4096 + ((wave << 4) + (rgrp << 2)) * 64 + cIdx;
#pragma unroll
  for (int n = 0; n < 4; ++n)
#pragma unroll
    for (int j = 0; j < 4; ++j) {
      float val = s_acc[n][j] * scale + bt[j * 64 + (n << 4)];
      s_acc[n][j] = val;
      mrow[j] = fmaxf(mrow[j], val);
    }
#pragma unroll
  for (int j = 0; j < 4; ++j)
#pragma unroll
    for (int o2 = 1; o2 < 16; o2 <<= 1) mrow[j] = fmaxf(mrow[j], __shfl_xor(mrow[j], o2, 64));
  float srow[4] = {0.f, 0.f, 0.f, 0.f};
#pragma unroll
  for (int n = 0; n < 4; ++n)
#pragma unroll
    for (int j = 0; j < 4; ++j) {
      float e = __expf(s_acc[n][j] - mrow[j]);
      s_acc[n][j] = e;
      srow[j] += e;
    }
#pragma unroll
  for (int j = 0; j < 4; ++j)
#pragma unroll
    for (int o2 = 1; o2 < 16; o2 <<= 1) srow[j] += __shfl_xor(srow[j], o2, 64);
  float rinv[4];
#pragma unroll
  for (int j = 0; j < 4; ++j) rinv[j] = 1.f / srow[j];
  u16* pw = p_s[wave];
#pragma unroll
  for (int n = 0; n < 4; ++n)
#pragma unroll
    for (int j = 0; j < 4; ++j)
      pw[((rgrp << 2) + j) * 72 + (n << 4) + cIdx] = f2bf(s_acc[n][j] * rinv[j]);
  f32x4 o_acc[2] = {};
#pragma unroll
  for (int kk = 0; kk < 2; ++kk) {
    bf16x8 pa = *(const bf16x8*)&pw[cIdx * 72 + (kk << 5) + (rgrp << 3)];
#pragma unroll
    for (int c2 = 0; c2 < 2; ++c2) {
      bf16x8 vb = *(const bf16x8*)&vt_s[((c2 << 4) + cIdx) * 64 + (kk << 5) + (rgrp << 3)];
      o_acc[c2] = __builtin_amdgcn_mfma_f32_16x16x32_bf16(pa, vb, o_acc[c2], 0, 0, 0);
    }
  }
#pragma unroll
  for (int c2 = 0; c2 < 2; ++c2)
#pragma unroll
    for (int j = 0; j < 4; ++j) {
      const int p = (wave << 4) + (rgrp << 2) + j;
      const int pr = p >> 3, pc = p & 7;
      const int orow = (wr0 + pr + 4) & 63, ocol = (wc0 + pc + 4) & 63;
      const size_t t = ((size_t)b << 12) + (orow << 6) + ocol;
      o[t * 384 + h * 32 + (c2 << 4) + cIdx] = f2bf(o_acc[c2][j]);
    }
}

extern "C" void kernel_launch(void* const* d_in, const int* in_sizes, int n_in,
                              void* d_out, int out_size, void* d_ws, size_t ws_size,
                              hipStream_t stream) {
  const float* x = (const float*)d_in[0];
  const float* n1g = (const float*)d_in[1];
  const float* n1b = (const float*)d_in[2];
  const float* qkv_w = (const float*)d_in[3];
  const float* qkv_b = (const float*)d_in[4];
  const float* proj_w = (const float*)d_in[5];
  const float* proj_b = (const float*)d_in[6];
  const float* rpb = (const float*)d_in[7];
  const float* n2g = (const float*)d_in[8];
  const float* n2b = (const float*)d_in[9];
  const float* fc1_w = (const float*)d_in[10];
  const float* fc1_b = (const float*)d_in[11];
  const float* fc2_w = (const float*)d_in[12];
  const float* fc2_b = (const float*)d_in[13];

  char* ws = (char*)d_ws;
  u16* wqkv = (u16*)(ws + 0);                // 442368 elems
  u16* wproj = (u16*)(ws + 884736);          // 147456
  u16* wfc1 = (u16*)(ws + 1179648);          // 589824
  u16* wfc2 = (u16*)(ws + 2359296);          // 589824
  float* bias_tab = (float*)(ws + 3538944);
  u16* qkv = (u16*)(ws + 3735552);           // region A (qkv, then m1)
  u16* m1 = qkv;
  u16* hbuf = (u16*)(ws + 205062144);        // region B (h -> o -> h2)
  u16* obuf = hbuf;
  float* x1 = (float*)d_out;                 // x1 lives in d_out

  cvt_all<<<(1769472 + 255) / 256, 256, 0, stream>>>(qkv_w, proj_w, fc1_w, fc2_w, wqkv);
  build_bias<<<192, 256, 0, stream>>>(rpb, bias_tab);

  ln_k<<<16384, 256, 0, stream>>>(x, n1g, n1b, hbuf);
  gemmA<0><<<4608, 256, 0, stream>>>(hbuf, wqkv, qkv_b, nullptr, qkv, 1152, 384, 9);
  attn_k<<<12288, 256, 0, stream>>>(qkv, bias_tab, obuf);
  gemmA<1><<<1536, 256, 0, stream>>>(obuf, wproj, proj_b, x, x1, 384, 384, 3);
  ln_k<<<16384, 256, 0, stream>>>(x1, n2g, n2b, hbuf);
  gemmA<2><<<6144, 256, 0, stream>>>(hbuf, wfc1, fc1_b, nullptr, m1, 1536, 384, 12);
  gemmA<3><<<1536, 256, 0, stream>>>(m1, wfc2, fc2_b, x1, (float*)d_out, 384, 1536, 3);
}